// Round 3
// baseline (1169.360 us; speedup 1.0000x reference)
//
#include <hip/hip_runtime.h>
#include <math.h>

// Problem constants (from setup_inputs)
#define NN   50000          // nodes
#define EE   800000         // edges (without self loops)
#define ETOT 850000         // edges + self loops
#define INF_FEATS 22
#define D1   256            // HEADS*HID
#define NH   4
#define D2   32
#define BN_EPS 1e-5f
#define NEG_SLOPE 0.2f

__device__ __forceinline__ void edge_sd(const int* __restrict__ ei, int e,
                                        int& s, int& d) {
    if (e < EE) { s = ei[e]; d = ei[EE + e]; }
    else        { s = d = e - EE; }
}

// sA: h1[n,col] = sum_k x[n,k] * W1[k,col]   (block = one node, thread = col)
__global__ __launch_bounds__(256) void sA(const float* __restrict__ x,
                                          const float* __restrict__ W1,
                                          float* __restrict__ h1) {
    const int n = blockIdx.x, col = threadIdx.x;
    float a = 0.f;
#pragma unroll
    for (int k = 0; k < INF_FEATS; ++k)
        a = fmaf(x[n * INF_FEATS + k], W1[k * D1 + col], a);
    h1[n * D1 + col] = a;
}

// sB: attention dots layer 1, thread per (n,h)
__global__ void sB(const float* __restrict__ h1, const float* __restrict__ atts,
                   const float* __restrict__ attd, float* __restrict__ as1,
                   float* __restrict__ ad1) {
    const int id = blockIdx.x * 256 + threadIdx.x;
    if (id >= NN * NH) return;
    const int n = id >> 2, h = id & 3;
    float s = 0.f, d = 0.f;
    for (int c = 0; c < 64; ++c) {
        const float v = h1[n * D1 + h * 64 + c];
        s = fmaf(v, atts[h * 64 + c], s);
        d = fmaf(v, attd[h * 64 + c], d);
    }
    as1[id] = s;
    ad1[id] = d;
}

// sC1: p = exp(leaky(a_src+a_dst)); store numerator; atomic segment-sum
__global__ void sC1(const int* __restrict__ ei, const float* __restrict__ as1,
                    const float* __restrict__ ad1, float* __restrict__ alpha1,
                    float* __restrict__ s1) {
    const int id = blockIdx.x * 256 + threadIdx.x;
    if (id >= ETOT * NH) return;
    const int e = id >> 2, h = id & 3;
    int s, d;
    edge_sd(ei, e, s, d);
    float a = as1[s * NH + h] + ad1[d * NH + h];
    a = (a >= 0.f) ? a : NEG_SLOPE * a;
    const float p = expf(a);
    alpha1[id] = p;
    atomicAdd(&s1[d * NH + h], p);
}

// sC2: normalize alpha in place
__global__ void sC2(const int* __restrict__ ei, float* __restrict__ alpha1,
                    const float* __restrict__ s1) {
    const int id = blockIdx.x * 256 + threadIdx.x;
    if (id >= ETOT * NH) return;
    const int e = id >> 2, h = id & 3;
    int s, d;
    edge_sd(ei, e, s, d);
    alpha1[id] /= (s1[d * NH + h] + 1e-16f);
}

// sD: message scatter layer 1: block = one edge, thread = col
__global__ __launch_bounds__(256) void sD(const int* __restrict__ ei,
                                          const float* __restrict__ alpha1,
                                          const float* __restrict__ h1,
                                          float* __restrict__ out1) {
    const int e = blockIdx.x, col = threadIdx.x;
    int s, d;
    edge_sd(ei, e, s, d);
    const float al = alpha1[e * NH + (col >> 6)];
    atomicAdd(&out1[d * D1 + col], al * h1[s * D1 + col]);
}

// sE: epilogue layer 1: +b1, BN1, ELU -> hpost
__global__ __launch_bounds__(256) void sE(const float* __restrict__ out1,
                                          const float* __restrict__ b1,
                                          const float* __restrict__ g1,
                                          const float* __restrict__ be1,
                                          const float* __restrict__ mu1,
                                          const float* __restrict__ va1,
                                          float* __restrict__ hpost) {
    const int n = blockIdx.x, col = threadIdx.x;
    float v = out1[n * D1 + col] + b1[col];
    v = (v - mu1[col]) * rsqrtf(va1[col] + BN_EPS) * g1[col] + be1[col];
    v = (v > 0.f) ? v : expm1f(v);
    hpost[n * D1 + col] = v;
}

// sF: h2[n,c] = sum_k hpost[n,k] * W2[k,c]; 8 nodes per block
__global__ __launch_bounds__(256) void sF(const float* __restrict__ hpost,
                                          const float* __restrict__ W2,
                                          float* __restrict__ h2) {
    const int t = threadIdx.x;
    const int n = blockIdx.x * 8 + (t >> 5), c = t & 31;
    float a = 0.f;
    for (int k = 0; k < D1; ++k)
        a = fmaf(hpost[n * D1 + k], W2[k * D2 + c], a);
    h2[n * D2 + c] = a;
}

// sG: attention dots layer 2, thread per n
__global__ void sG(const float* __restrict__ h2, const float* __restrict__ atts,
                   const float* __restrict__ attd, float* __restrict__ as2,
                   float* __restrict__ ad2) {
    const int n = blockIdx.x * 256 + threadIdx.x;
    if (n >= NN) return;
    float s = 0.f, d = 0.f;
    for (int c = 0; c < D2; ++c) {
        const float v = h2[n * D2 + c];
        s = fmaf(v, atts[c], s);
        d = fmaf(v, attd[c], d);
    }
    as2[n] = s;
    ad2[n] = d;
}

// sH1: layer-2 numerators + segment sum
__global__ void sH1(const int* __restrict__ ei, const float* __restrict__ as2,
                    const float* __restrict__ ad2, float* __restrict__ alpha2,
                    float* __restrict__ s2) {
    const int e = blockIdx.x * 256 + threadIdx.x;
    if (e >= ETOT) return;
    int s, d;
    edge_sd(ei, e, s, d);
    float a = as2[s] + ad2[d];
    a = (a >= 0.f) ? a : NEG_SLOPE * a;
    const float p = expf(a);
    alpha2[e] = p;
    atomicAdd(&s2[d], p);
}

// sH2: normalize
__global__ void sH2(const int* __restrict__ ei, float* __restrict__ alpha2,
                    const float* __restrict__ s2) {
    const int e = blockIdx.x * 256 + threadIdx.x;
    if (e >= ETOT) return;
    int s, d;
    edge_sd(ei, e, s, d);
    alpha2[e] /= (s2[d] + 1e-16f);
}

// sI: message scatter layer 2: 8 edges per block, 32 cols each
__global__ __launch_bounds__(256) void sI(const int* __restrict__ ei,
                                          const float* __restrict__ alpha2,
                                          const float* __restrict__ h2,
                                          float* __restrict__ out2) {
    const int t = threadIdx.x;
    const int e = blockIdx.x * 8 + (t >> 5), c = t & 31;
    int s, d;
    edge_sd(ei, e, s, d);
    atomicAdd(&out2[d * D2 + c], alpha2[e] * h2[s * D2 + c]);
}

// sJ: epilogue layer 2: +b2, BN2, ELU -> out; 8 nodes per block
__global__ __launch_bounds__(256) void sJ(const float* __restrict__ out2,
                                          const float* __restrict__ b2,
                                          const float* __restrict__ g2,
                                          const float* __restrict__ be2,
                                          const float* __restrict__ mu2,
                                          const float* __restrict__ va2,
                                          float* __restrict__ out) {
    const int t = threadIdx.x;
    const int n = blockIdx.x * 8 + (t >> 5), c = t & 31;
    float v = out2[n * D2 + c] + b2[c];
    v = (v - mu2[c]) * rsqrtf(va2[c] + BN_EPS) * g2[c] + be2[c];
    v = (v > 0.f) ? v : expm1f(v);
    out[n * D2 + c] = v;
}

// ---------------------------------------------------------------------------
extern "C" void kernel_launch(void* const* d_in, const int* in_sizes, int n_in,
                              void* d_out, int out_size, void* d_ws, size_t ws_size,
                              hipStream_t stream) {
    (void)in_sizes; (void)n_in; (void)out_size; (void)ws_size;
    const float* x   = (const float*)d_in[0];
    const int*   ei  = (const int*)  d_in[1];
    const float* W1  = (const float*)d_in[2];
    const float* as1i = (const float*)d_in[3];
    const float* ad1i = (const float*)d_in[4];
    const float* b1  = (const float*)d_in[5];
    const float* W2  = (const float*)d_in[6];
    const float* as2i = (const float*)d_in[7];
    const float* ad2i = (const float*)d_in[8];
    const float* b2  = (const float*)d_in[9];
    const float* g1  = (const float*)d_in[10];
    const float* be1 = (const float*)d_in[11];
    const float* mu1 = (const float*)d_in[12];
    const float* va1 = (const float*)d_in[13];
    const float* g2  = (const float*)d_in[14];
    const float* be2 = (const float*)d_in[15];
    const float* mu2 = (const float*)d_in[16];
    const float* va2 = (const float*)d_in[17];
    float* out = (float*)d_out;

    // workspace layout (floats), with careful lifetime-based overlays:
    //   h1    [12.8M]  (hpost aliases h1: h1 dead after sD)
    //   out1  [12.8M]  (out2 aliases out1: out1 dead after sE)
    //   as1/ad1/s1 [0.6M]
    //   alpha1[3.4M]   (h2 + as2 + ad2 + s2 + alpha2 alias alpha1's region:
    //                   alpha1 dead after sD; 1.6+0.05*3+0.85 = 2.6M <= 3.4M)
    float* ws = (float*)d_ws;
    float* h1     = ws;                               // NN*256
    float* out1   = h1 + (size_t)NN * D1;             // NN*256
    float* as1    = out1 + (size_t)NN * D1;           // NN*4
    float* ad1    = as1 + (size_t)NN * NH;            // NN*4
    float* s1     = ad1 + (size_t)NN * NH;            // NN*4
    float* alpha1 = s1 + (size_t)NN * NH;             // ETOT*4
    // overlays (used only after their hosts are dead):
    float* hpost  = h1;                               // NN*256 (after sD)
    float* h2     = alpha1;                           // NN*32  (after sD)
    float* as2    = h2 + (size_t)NN * D2;             // NN
    float* ad2    = as2 + NN;                         // NN
    float* s2     = ad2 + NN;                         // NN
    float* alpha2 = s2 + NN;                          // ETOT
    float* out2   = out1;                             // NN*32  (after sE)

    // ---- layer 1 ----
    hipMemsetAsync(s1, 0, (size_t)NN * NH * sizeof(float), stream);
    hipMemsetAsync(out1, 0, (size_t)NN * D1 * sizeof(float), stream);
    sA<<<NN, 256, 0, stream>>>(x, W1, h1);
    sB<<<(NN * NH + 255) / 256, 256, 0, stream>>>(h1, as1i, ad1i, as1, ad1);
    sC1<<<(ETOT * NH + 255) / 256, 256, 0, stream>>>(ei, as1, ad1, alpha1, s1);
    sC2<<<(ETOT * NH + 255) / 256, 256, 0, stream>>>(ei, alpha1, s1);
    sD<<<ETOT, 256, 0, stream>>>(ei, alpha1, h1, out1);
    sE<<<NN, 256, 0, stream>>>(out1, b1, g1, be1, mu1, va1, hpost);

    // ---- layer 2 ----
    hipMemsetAsync(s2, 0, (size_t)NN * sizeof(float), stream);
    hipMemsetAsync(out2, 0, (size_t)NN * D2 * sizeof(float), stream);
    sF<<<NN / 8, 256, 0, stream>>>(hpost, W2, h2);
    sG<<<(NN + 255) / 256, 256, 0, stream>>>(h2, as2i, ad2i, as2, ad2);
    sH1<<<(ETOT + 255) / 256, 256, 0, stream>>>(ei, as2, ad2, alpha2, s2);
    sH2<<<(ETOT + 255) / 256, 256, 0, stream>>>(ei, alpha2, s2);
    sI<<<ETOT / 8, 256, 0, stream>>>(ei, alpha2, h2, out2);
    sJ<<<NN / 8, 256, 0, stream>>>(out2, b2, g2, be2, mu2, va2, out);
}

// Round 4
// 690.820 us; speedup vs baseline: 1.6927x; 1.6927x over previous
//
#include <hip/hip_runtime.h>
#include <math.h>

// Problem constants (from setup_inputs)
#define NN   50000          // nodes
#define EE   800000         // edges (without self loops)
#define ETOT 850000         // edges + self loops
#define INF_FEATS 22
#define D1   256            // HEADS*HID
#define NH   4
#define D2   32
#define BN_EPS 1e-5f
#define NEG_SLOPE 0.2f

// ---------------------------------------------------------------------------
// sA: h1[n,col] = sum_k x[n,k] * W1[k,col]   (block = one node, thread = col)
__global__ __launch_bounds__(256) void sA(const float* __restrict__ x,
                                          const float* __restrict__ W1,
                                          float* __restrict__ h1) {
    const int n = blockIdx.x, col = threadIdx.x;
    float a = 0.f;
#pragma unroll
    for (int k = 0; k < INF_FEATS; ++k)
        a = fmaf(x[n * INF_FEATS + k], W1[k * D1 + col], a);
    h1[n * D1 + col] = a;
}

// sB: attention dots layer 1, thread per (n,h)
__global__ void sB(const float* __restrict__ h1, const float* __restrict__ atts,
                   const float* __restrict__ attd, float* __restrict__ as1,
                   float* __restrict__ ad1) {
    const int id = blockIdx.x * 256 + threadIdx.x;
    if (id >= NN * NH) return;
    const int n = id >> 2, h = id & 3;
    float s = 0.f, d = 0.f;
    for (int c = 0; c < 64; ++c) {
        const float v = h1[n * D1 + h * 64 + c];
        s = fmaf(v, atts[h * 64 + c], s);
        d = fmaf(v, attd[h * 64 + c], d);
    }
    as1[id] = s;
    ad1[id] = d;
}

// ---------------------------------------------------------------------------
// CSR build: count / scan / scatter  (dst-sorted adjacency)
__global__ void c_count(const int* __restrict__ ei, int* __restrict__ cnt) {
    int e = blockIdx.x * blockDim.x + threadIdx.x;
    if (e >= ETOT) return;
    int dst = (e < EE) ? ei[EE + e] : (e - EE);
    atomicAdd(&cnt[dst], 1);
}

__global__ __launch_bounds__(1024) void c_scan(
    const int* __restrict__ cnt, int* __restrict__ offs, int* __restrict__ cur) {
    __shared__ int part[1024];
    const int C = (NN + 1023) / 1024;  // 49
    const int t = threadIdx.x;
    const int beg = t * C, end = min(beg + C, NN);
    int s = 0;
    for (int i = beg; i < end; ++i) s += cnt[i];
    part[t] = s;
    __syncthreads();
    for (int off = 1; off < 1024; off <<= 1) {
        int v = (t >= off) ? part[t - off] : 0;
        __syncthreads();
        part[t] += v;
        __syncthreads();
    }
    int run = (t == 0) ? 0 : part[t - 1];  // exclusive prefix of this chunk
    for (int i = beg; i < end; ++i) {
        offs[i] = run;
        cur[i] = run;
        run += cnt[i];
    }
    if (t == 1023) offs[NN] = part[1023];
}

__global__ void c_scatter(const int* __restrict__ ei, int* __restrict__ cur,
                          int* __restrict__ ssrc) {
    int e = blockIdx.x * blockDim.x + threadIdx.x;
    if (e >= ETOT) return;
    int src, dst;
    if (e < EE) { src = ei[e]; dst = ei[EE + e]; }
    else        { src = dst = e - EE; }
    int pos = atomicAdd(&cur[dst], 1);
    ssrc[pos] = src;
}

// ---------------------------------------------------------------------------
// g1: layer-1 gather. Block = dst node, thread = col, wave = head.
// alpha recomputed inline (no max-shift: |logit| <= ~6, exp safe in f32).
// Fused +b1, BN1, ELU -> hpost.
__global__ __launch_bounds__(256) void g1k(
    const float* __restrict__ h1, const float* __restrict__ as1,
    const float* __restrict__ ad1, const int* __restrict__ offs,
    const int* __restrict__ ssrc, const float* __restrict__ b1,
    const float* __restrict__ g1, const float* __restrict__ be1,
    const float* __restrict__ mu1, const float* __restrict__ va1,
    float* __restrict__ hpost) {
    const int n = blockIdx.x, col = threadIdx.x, w = col >> 6;
    const int off = offs[n];
    const int deg = offs[n + 1] - off;
    const float adst = ad1[n * NH + w];
    float ssum = 0.f, acc = 0.f;
    for (int p = 0; p < deg; ++p) {
        const int sj = ssrc[off + p];                 // wave-uniform
        float a = as1[sj * NH + w] + adst;            // wave-uniform
        a = (a >= 0.f) ? a : NEG_SLOPE * a;
        const float al = __expf(a);
        ssum += al;
        acc = fmaf(al, h1[sj * D1 + col], acc);
    }
    float v = acc / (ssum + 1e-16f) + b1[col];
    v = (v - mu1[col]) * rsqrtf(va1[col] + BN_EPS) * g1[col] + be1[col];
    v = (v > 0.f) ? v : expm1f(v);
    hpost[n * D1 + col] = v;
}

// ---------------------------------------------------------------------------
// sF: h2[n,c] = sum_k hpost[n,k] * W2[k,c]; 8 nodes per block (32 lanes each)
__global__ __launch_bounds__(256) void sF(const float* __restrict__ hpost,
                                          const float* __restrict__ W2,
                                          float* __restrict__ h2) {
    const int t = threadIdx.x;
    const int n = blockIdx.x * 8 + (t >> 5), c = t & 31;
    float a = 0.f;
    for (int k = 0; k < D1; ++k)
        a = fmaf(hpost[n * D1 + k], W2[k * D2 + c], a);
    h2[n * D2 + c] = a;
}

// sG: attention dots layer 2, thread per n
__global__ void sG(const float* __restrict__ h2, const float* __restrict__ atts,
                   const float* __restrict__ attd, float* __restrict__ as2,
                   float* __restrict__ ad2) {
    const int n = blockIdx.x * 256 + threadIdx.x;
    if (n >= NN) return;
    float s = 0.f, d = 0.f;
    for (int c = 0; c < D2; ++c) {
        const float v = h2[n * D2 + c];
        s = fmaf(v, atts[c], s);
        d = fmaf(v, attd[c], d);
    }
    as2[n] = s;
    ad2[n] = d;
}

// ---------------------------------------------------------------------------
// g2: layer-2 gather. 8 nodes per block, 32 lanes per node.
// Fused +b2, BN2, ELU -> out (d_out).
__global__ __launch_bounds__(256) void g2k(
    const float* __restrict__ h2, const float* __restrict__ as2,
    const float* __restrict__ ad2, const int* __restrict__ offs,
    const int* __restrict__ ssrc, const float* __restrict__ b2,
    const float* __restrict__ g2, const float* __restrict__ be2,
    const float* __restrict__ mu2, const float* __restrict__ va2,
    float* __restrict__ out) {
    const int t = threadIdx.x;
    const int n = blockIdx.x * 8 + (t >> 5), c = t & 31;  // grid exact: 6250*8
    const int off = offs[n];
    const int deg = offs[n + 1] - off;
    const float adst = ad2[n];
    float ssum = 0.f, acc = 0.f;
    for (int p = 0; p < deg; ++p) {
        const int sj = ssrc[off + p];
        float a = as2[sj] + adst;
        a = (a >= 0.f) ? a : NEG_SLOPE * a;
        const float al = __expf(a);
        ssum += al;
        acc = fmaf(al, h2[sj * D2 + c], acc);
    }
    float v = acc / (ssum + 1e-16f) + b2[c];
    v = (v - mu2[c]) * rsqrtf(va2[c] + BN_EPS) * g2[c] + be2[c];
    v = (v > 0.f) ? v : expm1f(v);
    out[n * D2 + c] = v;
}

// ---------------------------------------------------------------------------
extern "C" void kernel_launch(void* const* d_in, const int* in_sizes, int n_in,
                              void* d_out, int out_size, void* d_ws, size_t ws_size,
                              hipStream_t stream) {
    (void)in_sizes; (void)n_in; (void)out_size; (void)ws_size;
    const float* x    = (const float*)d_in[0];
    const int*   ei   = (const int*)  d_in[1];
    const float* W1   = (const float*)d_in[2];
    const float* as1i = (const float*)d_in[3];
    const float* ad1i = (const float*)d_in[4];
    const float* b1   = (const float*)d_in[5];
    const float* W2   = (const float*)d_in[6];
    const float* as2i = (const float*)d_in[7];
    const float* ad2i = (const float*)d_in[8];
    const float* b2   = (const float*)d_in[9];
    const float* g1   = (const float*)d_in[10];
    const float* be1  = (const float*)d_in[11];
    const float* mu1  = (const float*)d_in[12];
    const float* va1  = (const float*)d_in[13];
    const float* g2   = (const float*)d_in[14];
    const float* be2  = (const float*)d_in[15];
    const float* mu2  = (const float*)d_in[16];
    const float* va2  = (const float*)d_in[17];
    float* out = (float*)d_out;

    // workspace layout (~114.9 MB, under the 118.4 MB proven in Round 3)
    float* ws = (float*)d_ws;
    float* h1    = ws;                         // NN*256 = 12.8M
    float* hpost = h1 + (size_t)NN * D1;       // NN*256 = 12.8M
    float* as1   = hpost + (size_t)NN * D1;    // NN*4
    float* ad1   = as1 + (size_t)NN * NH;      // NN*4
    float* as2   = ad1 + (size_t)NN * NH;      // NN
    float* ad2   = as2 + NN;                   // NN
    float* h2    = ad2 + NN;                   // NN*32 = 1.6M
    int* cnt  = (int*)(h2 + (size_t)NN * D2);  // NN
    int* offs = cnt + NN;                      // NN+1
    int* cur  = offs + NN + 1;                 // NN
    int* ssrc = cur + NN;                      // ETOT

    hipMemsetAsync(cnt, 0, NN * sizeof(int), stream);

    // node features + attention dots (layer 1)
    sA<<<NN, 256, 0, stream>>>(x, W1, h1);
    sB<<<(NN * NH + 255) / 256, 256, 0, stream>>>(h1, as1i, ad1i, as1, ad1);
    // CSR build
    c_count<<<(ETOT + 255) / 256, 256, 0, stream>>>(ei, cnt);
    c_scan<<<1, 1024, 0, stream>>>(cnt, offs, cur);
    c_scatter<<<(ETOT + 255) / 256, 256, 0, stream>>>(ei, cur, ssrc);
    // layer-1 gather (softmax + aggregate + BN + ELU)
    g1k<<<NN, 256, 0, stream>>>(h1, as1, ad1, offs, ssrc,
                                b1, g1, be1, mu1, va1, hpost);
    // layer 2
    sF<<<NN / 8, 256, 0, stream>>>(hpost, W2, h2);
    sG<<<(NN + 255) / 256, 256, 0, stream>>>(h2, as2i, ad2i, as2, ad2);
    g2k<<<NN / 8, 256, 0, stream>>>(h2, as2, ad2, offs, ssrc,
                                    b2, g2, be2, mu2, va2, out);
}